// Round 9
// baseline (264.214 us; speedup 1.0000x reference)
//
#include <hip/hip_runtime.h>
#include <cstdint>
#include <cstddef>

// Problem constants (from reference): N=16384, D=256.
#define NV   16384
#define DD   256
#define NCH  (NV / 64)      // 256 chunks of 64 vertices
#define ECAP 23             // max "older" lower neighbors stored (P(Poisson(8)>23)~1e-5)

// ---------------------------------------------------------------------------
// K_prep (parallel): per vertex v (chunk ch = v>>6):
//  - masks_g[v] = uint4{ inmask.lo, inmask.hi, prevmask.lo, prevmask.hi }
//      inmask: lower nbrs in own chunk (bit j-chbase)
//      prevmask: nbrs in previous chunk (bit j-prevbase; all are lower)
//  - ext planes: u16 slot m of v lives at ext16[(m>>3)*(NV*8) + v*8 + (m&7)]
//      slot 0 = count of older lower nbrs (j < chbase-64), slots 1..23 = ids.
//      (plane-interleaved so k_mis loads 3 coalesced uint4 per vertex)
// ---------------------------------------------------------------------------
__global__ __launch_bounds__(256)
void k_prep(const int* __restrict__ nbr, const int* __restrict__ deg,
            int maxdeg, int n, uint4* __restrict__ masks_g,
            unsigned short* __restrict__ ext16)
{
    int v = blockIdx.x * 256 + threadIdx.x;
    if (v >= n) return;
    const int chbase   = v & ~63;
    const int prevbase = chbase - 64;
    const int dv = deg[v];
    const int* __restrict__ row = nbr + (size_t)v * (size_t)maxdeg;
    unsigned long long inm = 0, pvm = 0;
    int cnt = 0;
    for (int k = 0; k < dv; ++k) {
        int j = row[k];
        if (j >= v) continue;
        if (j >= chbase)        inm |= 1ull << (j - chbase);
        else if (j >= prevbase) pvm |= 1ull << (j - prevbase);
        else {
            if (cnt < ECAP) {
                int m = 1 + cnt;   // u16 slot
                ext16[((size_t)(m >> 3) << 17) + ((size_t)v << 3) + (m & 7)]
                    = (unsigned short)j;
            }
            ++cnt;
        }
    }
    ext16[(size_t)v << 3] = (unsigned short)(cnt > 65535 ? 65535 : cnt);
    masks_g[v] = make_uint4((unsigned)inm, (unsigned)(inm >> 32),
                            (unsigned)pvm, (unsigned)(pvm >> 32));
}

// ---------------------------------------------------------------------------
// K_mis: lexicographic greedy MIS, ONE wave, ZERO barriers.
// Per chunk c (64 vertices, 1/lane):
//   fixpoint in REGISTERS via __ballot (in-chunk lower mask L);
//   prev-chunk via (prevmask & Hprev); older nbrs via LDS byte probes of
//   FINAL statuses, issued one chunk early (pinned by sched_barrier) so their
//   latency hides under the previous fixpoint. Global masks/ext prefetched
//   3 chunks ahead in a 4-gen register pipeline (4x unrolled, static roles).
// ---------------------------------------------------------------------------
__global__ __launch_bounds__(64, 1)
void k_mis(const int* __restrict__ nbr, const int* __restrict__ deg,
           int maxdeg, int n,
           const uint4* __restrict__ masks_g, const uint4* __restrict__ extp,
           int* __restrict__ headlist, float* __restrict__ out_tail)
{
    __shared__ __align__(16) unsigned char st[NV + 64];   // +pad, st[NV]=0 sentinel
    __shared__ unsigned long long Hm[NCH];
    const int lane = threadIdx.x;

    for (int i = lane; i < (NV + 64) / 16; i += 64)
        ((uint4*)st)[i] = make_uint4(0u, 0u, 0u, 0u);

    // prologue: load generations for chunks 0,1,2
    uint4 M0 = make_uint4(0,0,0,0), M1 = M0, M2 = M0, M3 = M0;
    uint4 E0a = M0, E0b = M0, E0c = M0, E1a = M0, E1b = M0, E1c = M0;
    uint4 E2a = M0, E2b = M0, E2c = M0, E3a = M0, E3b = M0, E3c = M0;
    {
        int v0 = lane, v1 = 64 + lane, v2 = 128 + lane;
        M0 = masks_g[v0]; M1 = masks_g[v1]; M2 = masks_g[v2];
        E0a = extp[v0]; E0b = extp[NV + v0]; E0c = extp[2*NV + v0];
        E1a = extp[v1]; E1b = extp[NV + v1]; E1c = extp[2*NV + v1];
        E2a = extp[v2]; E2b = extp[NV + v2]; E2c = extp[2*NV + v2];
    }
    bool extH = false;
    unsigned long long Hprev = 0ull;

#define PRBL(K, W, S) q##K = st[((K) < cntN) ? (((W) >> (S)) & 0x3FFFu) : NV];

#define BODY(CUR, MC, ENa, ENb, ENc, MLD, ELa, ELb, ELc)                        \
do {                                                                            \
    const int  _cur = (CUR);                                                    \
    const bool _nx  = (_cur + 1 < NCH);                                         \
    int cntN = 0;                                                               \
    int q0=0,q1=0,q2=0,q3=0,q4=0,q5=0,q6=0,q7=0,q8=0,q9=0,q10=0,q11=0;          \
    int q12=0,q13=0,q14=0,q15=0,q16=0,q17=0,q18=0,q19=0,q20=0,q21=0,q22=0;      \
    if (_nx) {          /* STEP1: probes for chunk CUR+1 (targets final) */     \
        cntN = (int)((ENa).x & 0xffffu);                                        \
        PRBL(0,  (ENa).x, 16) PRBL(1,  (ENa).y, 0)  PRBL(2,  (ENa).y, 16)       \
        PRBL(3,  (ENa).z, 0)  PRBL(4,  (ENa).z, 16) PRBL(5,  (ENa).w, 0)        \
        PRBL(6,  (ENa).w, 16) PRBL(7,  (ENb).x, 0)  PRBL(8,  (ENb).x, 16)       \
        PRBL(9,  (ENb).y, 0)  PRBL(10, (ENb).y, 16) PRBL(11, (ENb).z, 0)        \
        PRBL(12, (ENb).z, 16) PRBL(13, (ENb).w, 0)  PRBL(14, (ENb).w, 16)       \
        PRBL(15, (ENc).x, 0)  PRBL(16, (ENc).x, 16) PRBL(17, (ENc).y, 0)        \
        PRBL(18, (ENc).y, 16) PRBL(19, (ENc).z, 0)  PRBL(20, (ENc).z, 16)       \
        PRBL(21, (ENc).w, 0)  PRBL(22, (ENc).w, 16)                             \
    }                                                                           \
    if (_cur + 3 < NCH) {   /* STEP2: global prefetch, 3 chunks ahead */        \
        const int _vl = (_cur + 3) * 64 + lane;                                 \
        (MLD) = masks_g[_vl];                                                   \
        (ELa) = extp[_vl]; (ELb) = extp[NV + _vl]; (ELc) = extp[2*NV + _vl];    \
    }                                                                           \
    __builtin_amdgcn_sched_barrier(0);  /* pin probes/loads above fixpoint */   \
    {                       /* STEP3: in-register greedy fixpoint */            \
        unsigned long long L = ((unsigned long long)(MC).y << 32) | (MC).x;     \
        unsigned long long P = ((unsigned long long)(MC).w << 32) | (MC).z;     \
        bool eH = extH || ((P & Hprev) != 0ull);                                \
        unsigned long long D = __ballot(eH), H = 0ull;                          \
        for (;;) {                                                              \
            bool und = ((D >> lane) & 1ull) == 0ull;                            \
            bool mkN = und && ((L & H) != 0ull);                                \
            bool mkH = und && !mkN && ((L & ~D) == 0ull);                       \
            unsigned long long nH = __ballot(mkH), nN = __ballot(mkN);          \
            H |= nH; D |= nH | nN;                                              \
            if (__ballot(und && !mkH && !mkN) == 0ull) break;                   \
        }                                                                       \
        st[_cur * 64 + lane] = (unsigned char)((((H >> lane) & 1ull)) ? 1 : 2); \
        if (lane == 0) Hm[_cur] = H;                                            \
        Hprev = H;                                                              \
    }                                                                           \
    if (_nx) {              /* STEP4: fold probes -> extH for CUR+1 */          \
        int orv = q0|q1|q2|q3|q4|q5|q6|q7|q8|q9|q10|q11|q12|q13|q14|q15         \
                |q16|q17|q18|q19|q20|q21|q22;                                   \
        bool anyOld = (orv & 1) != 0;   /* codes: head=1, nonhead=2 */          \
        if (cntN > ECAP) {              /* rare fallback: walk global row */    \
            const int _vN = (_cur + 1) * 64 + lane;                             \
            const int _dvf = deg[_vN];                                          \
            const int* __restrict__ _row = nbr + (size_t)_vN * (size_t)maxdeg;  \
            const int _lim = _cur * 64;                                         \
            for (int _k = 0; _k < _dvf; ++_k) {                                 \
                int _j = _row[_k];                                              \
                if (_j < _lim) anyOld |= (st[_j] == 1);                         \
            }                                                                   \
        }                                                                       \
        extH = anyOld;                                                          \
    } else extH = false;                                                        \
} while (0)

    for (int c0 = 0; c0 < NCH; c0 += 4) {
        BODY(c0 + 0, M0, E1a, E1b, E1c, M3, E3a, E3b, E3c);
        BODY(c0 + 1, M1, E2a, E2b, E2c, M0, E0a, E0b, E0c);
        BODY(c0 + 2, M2, E3a, E3b, E3c, M1, E1a, E1b, E1c);
        BODY(c0 + 3, M3, E0a, E0b, E0c, M2, E2a, E2b, E2c);
    }
#undef BODY
#undef PRBL

    // ---- epilogue (single wave): scan head counts, emit outputs ----
    // lane owns chunks [4*lane, 4*lane+4) -> contiguous vertex ranges
    unsigned long long h0 = Hm[4*lane], h1 = Hm[4*lane+1],
                       h2 = Hm[4*lane+2], h3 = Hm[4*lane+3];
    int cnt = __popcll(h0) + __popcll(h1) + __popcll(h2) + __popcll(h3);
    int c = cnt;
    #pragma unroll
    for (int off = 1; off < 64; off <<= 1) {
        int x = __shfl_up(c, off);
        if (lane >= off) c += x;
    }
    int excl = c - cnt;
    #pragma unroll
    for (int i = 0; i < 4; ++i) {
        unsigned long long h = (i == 0) ? h0 : (i == 1) ? h1 : (i == 2) ? h2 : h3;
        const int base = (4*lane + i) * 64;
        while (h) {
            int b = __ffsll((long long)h) - 1;
            h &= h - 1;
            headlist[excl++] = base + b;
        }
    }
    // head_mask floats, coalesced float4 stores
    for (int i = 0; i < 64; ++i) {
        unsigned long long w = Hm[i*4 + (lane >> 4)];
        int sh = (lane & 15) * 4;
        float4 f;
        f.x = (float)((w >> (sh+0)) & 1ull); f.y = (float)((w >> (sh+1)) & 1ull);
        f.z = (float)((w >> (sh+2)) & 1ull); f.w = (float)((w >> (sh+3)) & 1ull);
        ((float4*)out_tail)[i*64 + lane] = f;
    }
    if (lane == 63) out_tail[n] = (float)c;   // inclusive scan at lane63 == total
}

// ---------------------------------------------------------------------------
// K_owner: 16 lanes per vertex. owner[v] = v if head else min head neighbor.
// ---------------------------------------------------------------------------
__global__ __launch_bounds__(256)
void k_owner(const int* __restrict__ nbr, const int* __restrict__ deg,
             int maxdeg, int n,
             const float* __restrict__ hm, int* __restrict__ owner)
{
    int gid = blockIdx.x * 256 + threadIdx.x;
    int v = gid >> 4, l = gid & 15;
    if (v >= n) return;
    if (hm[v] != 0.0f) { if (l == 0) owner[v] = v; return; }
    const int* __restrict__ row = nbr + (size_t)v * (size_t)maxdeg;
    const int dv = deg[v];
    int mn = 0x7fffffff;
    for (int k = l; k < dv; k += 16) {
        int j = row[k];
        if (hm[j] != 0.0f) mn = min(mn, j);
    }
    #pragma unroll
    for (int off = 8; off; off >>= 1) mn = min(mn, __shfl_xor(mn, off, 16));
    if (l == 0) owner[v] = mn;
}

// ---------------------------------------------------------------------------
// K_avg: one 64-lane wave per output row. Waves [0,tot): cluster mean for
// headlist[w]. Waves [tot,n): zero-fill the row (replaces the memset).
// ---------------------------------------------------------------------------
__global__ __launch_bounds__(256)
void k_avg(const float* __restrict__ vert, const int* __restrict__ nbr,
           const int* __restrict__ deg, int maxdeg, int n,
           const int* __restrict__ headlist, const int* __restrict__ owner,
           const float* __restrict__ tail, float* __restrict__ out)
{
    const int w    = (blockIdx.x * 256 + threadIdx.x) >> 6;
    const int lane = threadIdx.x & 63;
    if (w >= n) return;
    const int tot  = (int)tail[n];
    if (w >= tot) {
        reinterpret_cast<float4*>(out + (size_t)w * DD)[lane] = make_float4(0.f, 0.f, 0.f, 0.f);
        return;
    }
    const int h = headlist[w];

    const int dh = deg[h];
    const int* __restrict__ row = nbr + (size_t)h * (size_t)maxdeg;

    float4 acc = reinterpret_cast<const float4*>(vert + (size_t)h * DD)[lane];
    int cnt = 1;

    for (int k0 = 0; k0 < dh; k0 += 64) {
        int k = k0 + lane;
        int j = (k < dh) ? row[k] : -1;
        bool mem = (j >= 0) && (owner[j] == h);
        unsigned long long m = __ballot(mem);
        cnt += __popcll(m);
        while (m) {
            int bit = __ffsll((long long)m) - 1;
            m &= (m - 1);
            int jj = __shfl(j, bit);
            float4 rr = reinterpret_cast<const float4*>(vert + (size_t)jj * DD)[lane];
            acc.x += rr.x; acc.y += rr.y; acc.z += rr.z; acc.w += rr.w;
        }
    }
    const float inv = 1.0f / (float)cnt;
    float4 res;
    res.x = acc.x * inv; res.y = acc.y * inv;
    res.z = acc.z * inv; res.w = acc.w * inv;
    reinterpret_cast<float4*>(out + (size_t)w * DD)[lane] = res;
}

// ---------------------------------------------------------------------------
extern "C" void kernel_launch(void* const* d_in, const int* in_sizes, int n_in,
                              void* d_out, int out_size, void* d_ws, size_t ws_size,
                              hipStream_t stream)
{
    const float* vert = (const float*)d_in[0];
    const int*   nbr  = (const int*)d_in[1];
    const int*   deg  = (const int*)d_in[2];

    const int n      = in_sizes[2];            // 16384
    const int maxdeg = in_sizes[1] / n;
    const int d      = in_sizes[0] / n;        // 256

    int*   owner    = (int*)d_ws;                                   // n ints
    int*   headlist = owner + n;                                    // n ints
    uint4* masks_g  = (uint4*)(headlist + n);                       // NV uint4 (256KB)
    unsigned short* ext16 = (unsigned short*)(masks_g + NV);        // NV*24 u16 (768KB)

    float* out      = (float*)d_out;
    float* out_tail = out + (size_t)n * (size_t)d;   // head_mask .. num_clusters

    hipLaunchKernelGGL(k_prep, dim3((n + 255) / 256), dim3(256), 0, stream,
                       nbr, deg, maxdeg, n, masks_g, ext16);

    hipLaunchKernelGGL(k_mis, dim3(1), dim3(64), 0, stream,
                       nbr, deg, maxdeg, n, masks_g, (const uint4*)ext16,
                       headlist, out_tail);

    hipLaunchKernelGGL(k_owner, dim3((n * 16 + 255) / 256), dim3(256), 0, stream,
                       nbr, deg, maxdeg, n, out_tail, owner);

    const int blocks = (n * 64 + 255) / 256;   // one wave per output row
    hipLaunchKernelGGL(k_avg, dim3(blocks), dim3(256), 0, stream,
                       vert, nbr, deg, maxdeg, n, headlist, owner, out_tail, out);
}

// Round 10
// 131.043 us; speedup vs baseline: 2.0162x; 2.0162x over previous
//
#include <hip/hip_runtime.h>
#include <cstdint>
#include <cstddef>

// Problem constants (from reference): N=16384, D=256.
#define NV 16384
#define DD 256
#define TPB 1024           // k_mis threads (16 waves), 1 vertex/thread/block
#define BLK 1024
#define PCAP 23            // pend capacity (P(Pois(8)>23) ~ 2e-6)
#define NPASS 4            // fast passes per round

// ---------------------------------------------------------------------------
// K_prep: per vertex v, ALL lower neighbors as u16 global ids, IN-BLOCK ONES
// FIRST (j in [blockbase, v)), then older (j < blockbase). 24 u16 slots in
// 3 uint4: slot0 = np | ni<<8 (np=total lower cnt clamped 255, ni=in-block
// cnt clamped 255), slots 1..23 = ids. Unused slots stay 0 (st[0] is a safe
// dummy probe target).
// ---------------------------------------------------------------------------
__global__ __launch_bounds__(256)
void k_prep(const int* __restrict__ nbr, const int* __restrict__ deg,
            int maxdeg, int n, uint4* __restrict__ pend_g)
{
    int v = blockIdx.x * 256 + threadIdx.x;
    if (v >= n) return;
    const int b  = v & ~(BLK - 1);
    const int dv = deg[v];
    const int* __restrict__ row = nbr + (size_t)v * (size_t)maxdeg;
    unsigned W0=0,W1=0,W2=0,W3=0,W4=0,W5=0,W6=0,W7=0,W8=0,W9=0,W10=0,W11=0;
    int cnt = 0;

#define PUT23(VAL) do { unsigned _e = (unsigned)(VAL);                         \
    switch (cnt) {                                                             \
        case 0:  W0  |= _e << 16; break;                                       \
        case 1:  W1  |= _e;       break;  case 2:  W1  |= _e << 16; break;     \
        case 3:  W2  |= _e;       break;  case 4:  W2  |= _e << 16; break;     \
        case 5:  W3  |= _e;       break;  case 6:  W3  |= _e << 16; break;     \
        case 7:  W4  |= _e;       break;  case 8:  W4  |= _e << 16; break;     \
        case 9:  W5  |= _e;       break;  case 10: W5  |= _e << 16; break;     \
        case 11: W6  |= _e;       break;  case 12: W6  |= _e << 16; break;     \
        case 13: W7  |= _e;       break;  case 14: W7  |= _e << 16; break;     \
        case 15: W8  |= _e;       break;  case 16: W8  |= _e << 16; break;     \
        case 17: W9  |= _e;       break;  case 18: W9  |= _e << 16; break;     \
        case 19: W10 |= _e;       break;  case 20: W10 |= _e << 16; break;     \
        case 21: W11 |= _e;       break;  case 22: W11 |= _e << 16; break;     \
        default: break;                                                        \
    } ++cnt; } while (0)

    // pass A: in-block lower neighbors first
    for (int k = 0; k < dv; ++k) {
        int j = row[k];
        if (j >= b && j < v) PUT23(j);
    }
    const int ni = cnt;
    // pass B: older lower neighbors (row is L1/L2-hot)
    for (int k = 0; k < dv; ++k) {
        int j = row[k];
        if (j < b) PUT23(j);
    }
#undef PUT23
    const int np = cnt;
    W0 |= (unsigned)((np > 255 ? 255 : np) | ((ni > 255 ? 255 : ni) << 8));
    pend_g[3 * (size_t)v]     = make_uint4(W0, W1, W2, W3);
    pend_g[3 * (size_t)v + 1] = make_uint4(W4, W5, W6, W7);
    pend_g[3 * (size_t)v + 2] = make_uint4(W8, W9, W10, W11);
}

// ---------------------------------------------------------------------------
// K_mis: lexicographic greedy MIS, single WG of 1024 threads, PURE PULL.
// st: 0=unknown, 1=head, 2=nonhead; each vertex writes ONLY its own byte.
// Per block: pass 0 probes ALL <=23 lower statuses (batched independent
// ds_read_u8; out-block targets are final -> verdict cached in prevH);
// round loop re-probes ONLY the <=8 in-block slots. 1 barrier per round
// (3-slot F protocol), common case 1 round/block.
// __launch_bounds__(1024,4): exactly 1 WG/CU -> VGPR cap 128, so the probe
// batch stays in registers instead of serializing (R7/R8's failure mode).
// ---------------------------------------------------------------------------
__global__ __launch_bounds__(TPB, 4)
void k_mis(const int* __restrict__ nbr, const int* __restrict__ deg,
           int maxdeg, int n, const uint4* __restrict__ pend_g,
           int* __restrict__ headlist, float* __restrict__ out_tail)
{
    __shared__ __align__(16) unsigned char st[NV];
    __shared__ int s_ws[TPB / 64];
    __shared__ int F[3];
    const int t    = threadIdx.x;
    const int lane = t & 63;
    const int wid  = t >> 6;

    ((uint4*)st)[t] = make_uint4(0u, 0u, 0u, 0u);   // 1024*16B == NV
    if (t < 3) F[t] = 0;
    __syncthreads();

    // prefetch block 0 (3 x uint4 per vertex), double-buffered across blocks
    uint4 pa = make_uint4(0,0,0,0), pb = pa, pc = pa;
    if (t < n) {
        pa = pend_g[3 * (size_t)t];
        pb = pend_g[3 * (size_t)t + 1];
        pc = pend_g[3 * (size_t)t + 2];
    }
    int r = 0;

    for (int b = 0; b < n; b += BLK) {
        uint4 qa = make_uint4(0,0,0,0), qb = qa, qc = qa;
        {
            int vn = b + BLK + t;
            if (vn < n) {
                qa = pend_g[3 * (size_t)vn];
                qb = pend_g[3 * (size_t)vn + 1];
                qc = pend_g[3 * (size_t)vn + 2];
            }
        }

        const int v  = b + t;
        const int np = (int)(pa.x & 0xFFu);
        const int ni = (int)((pa.x >> 8) & 0xFFu);
        const bool ovf = (np > PCAP);
        const int e0 = pa.x >> 16;
        const int e1 = pa.y & 0xFFFF, e2 = pa.y >> 16;
        const int e3 = pa.z & 0xFFFF, e4 = pa.z >> 16;
        const int e5 = pa.w & 0xFFFF, e6 = pa.w >> 16;
        const int e7 = pb.x & 0xFFFF;

        int my = (v < n) ? 0 : 2;
        int dvf = 0;
        if (my == 0 && ovf) dvf = deg[v];
        bool prevH = false;

        // ---- pass 0: full probe (out-block slots are FINAL) ----
        if (my == 0) {
            if (!ovf) {
                const int e8  = pb.x >> 16, e9  = pb.y & 0xFFFF, e10 = pb.y >> 16;
                const int e11 = pb.z & 0xFFFF, e12 = pb.z >> 16;
                const int e13 = pb.w & 0xFFFF, e14 = pb.w >> 16;
                const int e15 = pc.x & 0xFFFF, e16 = pc.x >> 16;
                const int e17 = pc.y & 0xFFFF, e18 = pc.y >> 16;
                const int e19 = pc.z & 0xFFFF, e20 = pc.z >> 16;
                const int e21 = pc.w & 0xFFFF, e22 = pc.w >> 16;
                // batched independent probes (unused slots read st[0], harmless)
                int q0=st[e0],  q1=st[e1],  q2=st[e2],  q3=st[e3],  q4=st[e4];
                int q5=st[e5],  q6=st[e6],  q7=st[e7],  q8=st[e8],  q9=st[e9];
                int q10=st[e10],q11=st[e11],q12=st[e12],q13=st[e13],q14=st[e14];
                int q15=st[e15],q16=st[e16],q17=st[e17],q18=st[e18],q19=st[e19];
                int q20=st[e20],q21=st[e21],q22=st[e22];
                bool inH = false, outH = false; int undec = 0;
                #define FOLD(K, QK)                                            \
                    { bool _in = (K) < ni, _vl = (K) < np;                     \
                      inH  |= _in && ((QK) == 1);                              \
                      outH |= (_vl && !_in) && ((QK) == 1);                    \
                      undec += (_in && ((QK) == 0)); }
                FOLD(0,q0)   FOLD(1,q1)   FOLD(2,q2)   FOLD(3,q3)   FOLD(4,q4)
                FOLD(5,q5)   FOLD(6,q6)   FOLD(7,q7)   FOLD(8,q8)   FOLD(9,q9)
                FOLD(10,q10) FOLD(11,q11) FOLD(12,q12) FOLD(13,q13) FOLD(14,q14)
                FOLD(15,q15) FOLD(16,q16) FOLD(17,q17) FOLD(18,q18) FOLD(19,q19)
                FOLD(20,q20) FOLD(21,q21) FOLD(22,q22)
                #undef FOLD
                prevH = outH;
                if (prevH || inH)    { my = 2; st[v] = 2; }
                else if (undec == 0) { my = 1; st[v] = 1; }
            } else {
                const int* __restrict__ row = nbr + (size_t)v * (size_t)maxdeg;
                bool anyH = false; int undec = 0;
                for (int k = 0; k < dvf; ++k) {
                    int j = row[k];
                    if (j < v) { int q = st[j]; anyH |= (q == 1); undec += (q == 0); }
                }
                if (anyH)            { my = 2; st[v] = 2; }
                else if (undec == 0) { my = 1; st[v] = 1; }
            }
        }

        // ---- rounds: fast passes over in-block slots only ----
        for (;; ++r) {
            if (t == 0) F[(r + 1) % 3] = 0;
            #pragma unroll
            for (int pass = 0; pass < NPASS; ++pass) {
                if (my == 0) {
                    bool anyH = false; int undec = 0;
                    if (!ovf && ni <= 8) {
                        int q0=st[e0], q1=st[e1], q2=st[e2], q3=st[e3];
                        int q4=st[e4], q5=st[e5], q6=st[e6], q7=st[e7];
                        #define FFOLD(K, QK) { bool _in = (K) < ni;            \
                            anyH |= _in && ((QK) == 1);                        \
                            undec += (_in && ((QK) == 0)); }
                        FFOLD(0,q0) FFOLD(1,q1) FFOLD(2,q2) FFOLD(3,q3)
                        FFOLD(4,q4) FFOLD(5,q5) FFOLD(6,q6) FFOLD(7,q7)
                        #undef FFOLD
                        anyH = anyH || prevH;
                    } else {
                        // rare: ni>8 or overflow -> full rescan
                        const int* __restrict__ row = nbr + (size_t)v * (size_t)maxdeg;
                        int lim = ovf ? dvf : 0;
                        if (!ovf) {
                            // full 23-slot probe via global ids in pend regs
                            const unsigned es[12] = {pa.x,pa.y,pa.z,pa.w,
                                                     pb.x,pb.y,pb.z,pb.w,
                                                     pc.x,pc.y,pc.z,pc.w};
                            // slot k id: k==0 -> es[0]>>16 ; else word (k+1)>>1, half (k+1)&1
                            for (int k = 0; k < np; ++k) {
                                int s  = k + 1;
                                unsigned w = es[s >> 1];
                                int id = (s & 1) ? (int)(w >> 16) : (int)(w & 0xFFFF);
                                int q = st[id];
                                anyH |= (q == 1);
                                undec += (k < ni) && (q == 0);
                            }
                        } else {
                            for (int k = 0; k < lim; ++k) {
                                int j = row[k];
                                if (j < v) { int q = st[j]; anyH |= (q == 1); undec += (q == 0); }
                            }
                        }
                    }
                    if (anyH)            { my = 2; st[v] = 2; }
                    else if (undec == 0) { my = 1; st[v] = 1; }
                }
                if (__ballot(my == 0) == 0ULL) break;   // wave-local early out
            }
            if (my == 0) F[r % 3] = 1;
            __syncthreads();
            if (F[r % 3] == 0) { ++r; break; }
        }
        pa = qa; pb = qb; pc = qc;
    }

    // ---- epilogue: count heads, scan, emit headlist / head_mask / count ----
    uint4 qq = ((const uint4*)st)[t];          // thread t owns bytes [16t,16t+16)
    int cnt = __popc(qq.x & 0x01010101u) + __popc(qq.y & 0x01010101u)
            + __popc(qq.z & 0x01010101u) + __popc(qq.w & 0x01010101u);
    int c = cnt;
    #pragma unroll
    for (int off = 1; off < 64; off <<= 1) {
        int x = __shfl_up(c, off);
        if (lane >= off) c += x;
    }
    if (lane == 63) s_ws[wid] = c;
    __syncthreads();
    int wexcl = 0, tot = 0;
    #pragma unroll
    for (int w = 0; w < TPB / 64; ++w) {
        int s = s_ws[w];
        tot += s;
        if (w < wid) wexcl += s;
    }
    int excl = wexcl + (c - cnt);
    #pragma unroll
    for (int i = 0; i < 16; ++i) {
        int v = t * 16 + i;
        if (st[v] == 1) { headlist[excl] = v; ++excl; }
    }
    for (int i = t; i < NV / 4; i += TPB) {
        unsigned w = ((const unsigned*)st)[i];
        float4 f;
        f.x = (float)(w & 1u);         f.y = (float)((w >> 8) & 1u);
        f.z = (float)((w >> 16) & 1u); f.w = (float)((w >> 24) & 1u);
        ((float4*)out_tail)[i] = f;
    }
    if (t == 0) out_tail[n] = (float)tot;
}

// ---------------------------------------------------------------------------
// K_owner: 16 lanes per vertex. owner[v] = v if head else min head neighbor.
// ---------------------------------------------------------------------------
__global__ __launch_bounds__(256)
void k_owner(const int* __restrict__ nbr, const int* __restrict__ deg,
             int maxdeg, int n,
             const float* __restrict__ hm, int* __restrict__ owner)
{
    int gid = blockIdx.x * 256 + threadIdx.x;
    int v = gid >> 4, l = gid & 15;
    if (v >= n) return;
    if (hm[v] != 0.0f) { if (l == 0) owner[v] = v; return; }
    const int* __restrict__ row = nbr + (size_t)v * (size_t)maxdeg;
    const int dv = deg[v];
    int mn = 0x7fffffff;
    for (int k = l; k < dv; k += 16) {
        int j = row[k];
        if (hm[j] != 0.0f) mn = min(mn, j);
    }
    #pragma unroll
    for (int off = 8; off; off >>= 1) mn = min(mn, __shfl_xor(mn, off, 16));
    if (l == 0) owner[v] = mn;
}

// ---------------------------------------------------------------------------
// K_avg: one 64-lane wave per output row. Waves [0,tot): cluster mean for
// headlist[w]. Waves [tot,n): zero-fill the row (replaces the memset).
// ---------------------------------------------------------------------------
__global__ __launch_bounds__(256)
void k_avg(const float* __restrict__ vert, const int* __restrict__ nbr,
           const int* __restrict__ deg, int maxdeg, int n,
           const int* __restrict__ headlist, const int* __restrict__ owner,
           const float* __restrict__ tail, float* __restrict__ out)
{
    const int w    = (blockIdx.x * 256 + threadIdx.x) >> 6;
    const int lane = threadIdx.x & 63;
    if (w >= n) return;
    const int tot  = (int)tail[n];
    if (w >= tot) {
        reinterpret_cast<float4*>(out + (size_t)w * DD)[lane] = make_float4(0.f, 0.f, 0.f, 0.f);
        return;
    }
    const int h = headlist[w];

    const int dh = deg[h];
    const int* __restrict__ row = nbr + (size_t)h * (size_t)maxdeg;

    float4 acc = reinterpret_cast<const float4*>(vert + (size_t)h * DD)[lane];
    int cnt = 1;

    for (int k0 = 0; k0 < dh; k0 += 64) {
        int k = k0 + lane;
        int j = (k < dh) ? row[k] : -1;
        bool mem = (j >= 0) && (owner[j] == h);
        unsigned long long m = __ballot(mem);
        cnt += __popcll(m);
        while (m) {
            int bit = __ffsll((long long)m) - 1;
            m &= (m - 1);
            int jj = __shfl(j, bit);
            float4 rr = reinterpret_cast<const float4*>(vert + (size_t)jj * DD)[lane];
            acc.x += rr.x; acc.y += rr.y; acc.z += rr.z; acc.w += rr.w;
        }
    }
    const float inv = 1.0f / (float)cnt;
    float4 res;
    res.x = acc.x * inv; res.y = acc.y * inv;
    res.z = acc.z * inv; res.w = acc.w * inv;
    reinterpret_cast<float4*>(out + (size_t)w * DD)[lane] = res;
}

// ---------------------------------------------------------------------------
extern "C" void kernel_launch(void* const* d_in, const int* in_sizes, int n_in,
                              void* d_out, int out_size, void* d_ws, size_t ws_size,
                              hipStream_t stream)
{
    const float* vert = (const float*)d_in[0];
    const int*   nbr  = (const int*)d_in[1];
    const int*   deg  = (const int*)d_in[2];

    const int n      = in_sizes[2];            // 16384
    const int maxdeg = in_sizes[1] / n;
    const int d      = in_sizes[0] / n;        // 256

    int*   owner    = (int*)d_ws;                                  // n ints
    int*   headlist = owner + n;                                   // n ints
    uint4* pend_g   = (uint4*)(headlist + n);                      // 3n uint4 (768KB)

    float* out      = (float*)d_out;
    float* out_tail = out + (size_t)n * (size_t)d;   // head_mask .. num_clusters

    hipLaunchKernelGGL(k_prep, dim3((n + 255) / 256), dim3(256), 0, stream,
                       nbr, deg, maxdeg, n, pend_g);

    hipLaunchKernelGGL(k_mis, dim3(1), dim3(TPB), 0, stream,
                       nbr, deg, maxdeg, n, pend_g, headlist, out_tail);

    hipLaunchKernelGGL(k_owner, dim3((n * 16 + 255) / 256), dim3(256), 0, stream,
                       nbr, deg, maxdeg, n, out_tail, owner);

    const int blocks = (n * 64 + 255) / 256;   // one wave per output row
    hipLaunchKernelGGL(k_avg, dim3(blocks), dim3(256), 0, stream,
                       vert, nbr, deg, maxdeg, n, headlist, owner, out_tail, out);
}

// Round 11
// 87.394 us; speedup vs baseline: 3.0232x; 1.4994x over previous
//
#include <hip/hip_runtime.h>
#include <cstdint>
#include <cstddef>

// Problem constants (from reference): N=16384, D=256.
#define NV 16384
#define DD 256
#define TPB 1024           // k_mis threads (16 waves), 1 vertex/thread/block
#define BLK 1024
#define PCAP 7             // in-block lower-neighbor cap (P(Pois(0.5)>7) ~ 1e-8)
#define HROW 24            // u16 slots per vertex in hi_g: [0]=count, [1..23]=higher nbrs
#define NPASS 8            // probe passes per barrier round (volatile -> real)

// volatile LDS byte read: forces re-read each pass (defeats CSE across passes)
#define VST(P, IDX) ((int)*((volatile const unsigned char*)(P) + (IDX)))

// ---------------------------------------------------------------------------
// K_prep (parallel, one pass over nbr): per vertex v emit
//  - pend_g[v] (uint4): in-1024-block lower neighbors as u16 offsets
//      x = count | e0<<16 ; y = e1|e2<<16 ; z = e3|e4<<16 ; w = e5|e6<<16
//  - hi_g[v*HROW..]: [count, up to 23 higher-neighbor vertex ids] (u16)
// ---------------------------------------------------------------------------
__global__ __launch_bounds__(256)
void k_prep(const int* __restrict__ nbr, const int* __restrict__ deg,
            int maxdeg, int n, uint4* __restrict__ pend_g,
            unsigned short* __restrict__ hi_g)
{
    int v = blockIdx.x * 256 + threadIdx.x;
    if (v >= n) return;
    const int b  = v & ~(BLK - 1);
    const int dv = deg[v];
    const int* __restrict__ row = nbr + (size_t)v * (size_t)maxdeg;
    unsigned short* __restrict__ hrow = hi_g + (size_t)v * HROW;
    unsigned w0 = 0, w1 = 0, w2 = 0, w3 = 0;
    int cnt = 0, hic = 0;
    for (int k = 0; k < dv; ++k) {
        int j = row[k];
        if (j > v) {
            if (hic < HROW - 1) hrow[1 + hic] = (unsigned short)j;
            ++hic;
        } else if (j >= b) {
            unsigned val = (unsigned)(j - b);
            switch (cnt) {
                case 0: w0 |= val << 16; break;
                case 1: w1 |= val;       break;
                case 2: w1 |= val << 16; break;
                case 3: w2 |= val;       break;
                case 4: w2 |= val << 16; break;
                case 5: w3 |= val;       break;
                case 6: w3 |= val << 16; break;
                default: break;
            }
            ++cnt;
        }
    }
    hrow[0] = (unsigned short)hic;
    w0 |= (unsigned)(cnt > 0xffff ? 0xffff : cnt);
    pend_g[v] = make_uint4(w0, w1, w2, w3);
}

// ---------------------------------------------------------------------------
// K_mis: lexicographic greedy MIS, single WG of 1024 threads (16 waves), PUSH.
// st: 0=unknown, 1=head, 2=nonhead (monotone -> LDS races benign).
// Heads push st=2 to higher neighbors from REGISTER-resident hi lists, so the
// out-of-block verdict is one volatile st[v] read. Per round: up to NPASS
// VOLATILE probe passes (the volatile defeats load-CSE, making passes real)
// with per-wave ballot early-exit; one drain-free barrier per round
// (s_waitcnt lgkmcnt(0) + s_barrier -> global prefetch stays in flight).
// ---------------------------------------------------------------------------
__global__ __launch_bounds__(TPB, 4)
void k_mis(const int* __restrict__ nbr, const int* __restrict__ deg,
           int maxdeg, int n,
           const uint4* __restrict__ pend_g, const unsigned short* __restrict__ hi_g,
           int* __restrict__ headlist, float* __restrict__ out_tail)
{
    __shared__ __align__(16) unsigned char st[NV];
    __shared__ int s_ws[TPB / 64];
    __shared__ int F[3];
    const int t    = threadIdx.x;
    const int lane = t & 63;
    const int wid  = t >> 6;

    ((uint4*)st)[t] = make_uint4(0u, 0u, 0u, 0u);   // 1024*16B == NV
    if (t < 3) F[t] = 0;
    __syncthreads();

    // prefetch block 0 (pend + hi row + deg), register double-buffered
    uint4 pv = make_uint4(0,0,0,0), h0 = pv, h1 = pv, h2 = pv;
    int   dv = 0;
    if (t < n) {
        pv = pend_g[t];
        const uint4* hp = (const uint4*)(hi_g + (size_t)t * HROW);
        h0 = hp[0]; h1 = hp[1]; h2 = hp[2];
        dv = deg[t];
    }
    int r = 0;

    for (int b = 0; b < n; b += BLK) {
        const int v = b + t;
        // prefetch next block; stays in flight across the drain-free barriers
        uint4 pn = make_uint4(0,0,0,0), n0 = pn, n1 = pn, n2 = pn;
        int   dn = 0;
        {
            int vn = b + BLK + t;
            if (vn < n) {
                pn = pend_g[vn];
                const uint4* hp = (const uint4*)(hi_g + (size_t)vn * HROW);
                n0 = hp[0]; n1 = hp[1]; n2 = hp[2];
                dn = deg[vn];
            }
        }

        const int np = pv.x & 0xffff;
        const int e0 = pv.x >> 16,    e1 = pv.y & 0xffff, e2 = pv.y >> 16;
        const int e3 = pv.z & 0xffff, e4 = pv.z >> 16;
        const int e5 = pv.w & 0xffff, e6 = pv.w >> 16;
        const int hic = (int)(h0.x & 0xffff);
        const int* __restrict__ row = nbr + (size_t)v * (size_t)maxdeg;

        int my = (v < n) ? 0 : 2;
        for (;; ++r) {
            if (t == 0) F[(r + 1) % 3] = 0;
            for (int pass = 0; pass < NPASS; ++pass) {
                if (my == 0) {
                    if (VST(st, v) != 0) { my = 2; }
                    else {
                        bool anyH = false; int undec = 0;
                        if (np <= PCAP) {
                            // 7 volatile probes, issued wave-wide, fold by np
                            int q0 = VST(st, b + e0), q1 = VST(st, b + e1);
                            int q2 = VST(st, b + e2), q3 = VST(st, b + e3);
                            int q4 = VST(st, b + e4), q5 = VST(st, b + e5);
                            int q6 = VST(st, b + e6);
                            if (np > 0) { anyH |= (q0 == 1); undec += (q0 == 0); }
                            if (np > 1) { anyH |= (q1 == 1); undec += (q1 == 0); }
                            if (np > 2) { anyH |= (q2 == 1); undec += (q2 == 0); }
                            if (np > 3) { anyH |= (q3 == 1); undec += (q3 == 0); }
                            if (np > 4) { anyH |= (q4 == 1); undec += (q4 == 0); }
                            if (np > 5) { anyH |= (q5 == 1); undec += (q5 == 0); }
                            if (np > 6) { anyH |= (q6 == 1); undec += (q6 == 0); }
                        } else {
                            for (int k = 0; k < dv; ++k) {
                                int j = row[k];
                                if (j >= b && j < v) {
                                    int q = VST(st, j);
                                    anyH |= (q == 1); undec += (q == 0);
                                }
                            }
                        }
                        if (anyH) { my = 2; st[v] = 2; }
                        else if (undec == 0) {
                            my = 1;
                            st[v] = 1;
                            if (hic <= HROW - 1) {
                                // push from registers: entry i at u16 slot 1+i
                                #define PUSHE(word, sh, k) if ((k) < hic) st[((word) >> (sh)) & 0xffffu] = 2
                                PUSHE(h0.x,16, 0); PUSHE(h0.y, 0, 1); PUSHE(h0.y,16, 2);
                                PUSHE(h0.z, 0, 3); PUSHE(h0.z,16, 4); PUSHE(h0.w, 0, 5);
                                PUSHE(h0.w,16, 6);
                                PUSHE(h1.x, 0, 7); PUSHE(h1.x,16, 8); PUSHE(h1.y, 0, 9);
                                PUSHE(h1.y,16,10); PUSHE(h1.z, 0,11); PUSHE(h1.z,16,12);
                                PUSHE(h1.w, 0,13); PUSHE(h1.w,16,14);
                                PUSHE(h2.x, 0,15); PUSHE(h2.x,16,16); PUSHE(h2.y, 0,17);
                                PUSHE(h2.y,16,18); PUSHE(h2.z, 0,19); PUSHE(h2.z,16,20);
                                PUSHE(h2.w, 0,21); PUSHE(h2.w,16,22);
                                #undef PUSHE
                            } else {
                                for (int k = 0; k < dv; ++k) {
                                    int j = row[k];
                                    if (j > v) st[j] = 2;
                                }
                            }
                        }
                    }
                }
                if (__ballot(my == 0) == 0ULL) break;   // wave-local early out
            }
            if (my == 0) F[r % 3] = 1;
            // drain-free barrier: LDS visible, global prefetch stays in flight
            asm volatile("s_waitcnt lgkmcnt(0)\n\ts_barrier" ::: "memory");
            if (F[r % 3] == 0) { ++r; break; }
        }
        pv = pn; h0 = n0; h1 = n1; h2 = n2; dv = dn;
    }

    // ---- epilogue: count heads, scan, emit headlist / head_mask / count ----
    uint4 qq = ((const uint4*)st)[t];          // thread t owns bytes [16t,16t+16)
    int cnt = __popc(qq.x & 0x01010101u) + __popc(qq.y & 0x01010101u)
            + __popc(qq.z & 0x01010101u) + __popc(qq.w & 0x01010101u);
    int c = cnt;
    #pragma unroll
    for (int off = 1; off < 64; off <<= 1) {
        int x = __shfl_up(c, off);
        if (lane >= off) c += x;
    }
    if (lane == 63) s_ws[wid] = c;
    __syncthreads();
    int wexcl = 0, tot = 0;
    #pragma unroll
    for (int w = 0; w < TPB / 64; ++w) {
        int s = s_ws[w];
        tot += s;
        if (w < wid) wexcl += s;
    }
    int excl = wexcl + (c - cnt);
    #pragma unroll
    for (int i = 0; i < 16; ++i) {
        int v = t * 16 + i;
        if (st[v] == 1) { headlist[excl] = v; ++excl; }
    }
    for (int i = t; i < NV / 4; i += TPB) {
        unsigned w = ((const unsigned*)st)[i];
        float4 f;
        f.x = (float)(w & 1u);         f.y = (float)((w >> 8) & 1u);
        f.z = (float)((w >> 16) & 1u); f.w = (float)((w >> 24) & 1u);
        ((float4*)out_tail)[i] = f;
    }
    if (t == 0) out_tail[n] = (float)tot;
}

// ---------------------------------------------------------------------------
// K_avg (fused owner+avg): one 64-lane wave per output row.
// Waves [0,tot): cluster mean for h=headlist[w]. Candidate j in row(h) is a
// member iff j nonhead AND min{head nbrs of j} == h (computed by walking j's
// row in-lane; j<h auto-excluded since its min head nbr < j < h).
// Waves [tot,n): zero-fill the row (replaces the memset).
// ---------------------------------------------------------------------------
__global__ __launch_bounds__(256)
void k_avg(const float* __restrict__ vert, const int* __restrict__ nbr,
           const int* __restrict__ deg, int maxdeg, int n,
           const int* __restrict__ headlist,
           const float* __restrict__ tail, float* __restrict__ out)
{
    const int w    = (blockIdx.x * 256 + threadIdx.x) >> 6;
    const int lane = threadIdx.x & 63;
    if (w >= n) return;
    const int tot  = (int)tail[n];
    if (w >= tot) {
        reinterpret_cast<float4*>(out + (size_t)w * DD)[lane] = make_float4(0.f, 0.f, 0.f, 0.f);
        return;
    }
    const int h = headlist[w];

    const int dh = deg[h];
    const int* __restrict__ row = nbr + (size_t)h * (size_t)maxdeg;

    float4 acc = reinterpret_cast<const float4*>(vert + (size_t)h * DD)[lane];
    int cnt = 1;

    for (int k0 = 0; k0 < dh; k0 += 64) {
        int k = k0 + lane;
        int j = (k < dh) ? row[k] : -1;
        bool mem = false;
        if (j > h && tail[j] == 0.0f) {        // nonhead, higher candidate
            // owner test: min head neighbor of j must be h
            const int dj = deg[j];
            const int* __restrict__ rj = nbr + (size_t)j * (size_t)maxdeg;
            int mn = 0x7fffffff;
            for (int kk = 0; kk < dj; ++kk) {
                int u = rj[kk];
                if (tail[u] != 0.0f) mn = min(mn, u);
            }
            mem = (mn == h);
        }
        unsigned long long m = __ballot(mem);
        cnt += __popcll(m);
        while (m) {
            int bit = __ffsll((long long)m) - 1;
            m &= (m - 1);
            int jj = __shfl(j, bit);
            float4 rr = reinterpret_cast<const float4*>(vert + (size_t)jj * DD)[lane];
            acc.x += rr.x; acc.y += rr.y; acc.z += rr.z; acc.w += rr.w;
        }
    }
    const float inv = 1.0f / (float)cnt;
    float4 res;
    res.x = acc.x * inv; res.y = acc.y * inv;
    res.z = acc.z * inv; res.w = acc.w * inv;
    reinterpret_cast<float4*>(out + (size_t)w * DD)[lane] = res;
}

// ---------------------------------------------------------------------------
extern "C" void kernel_launch(void* const* d_in, const int* in_sizes, int n_in,
                              void* d_out, int out_size, void* d_ws, size_t ws_size,
                              hipStream_t stream)
{
    const float* vert = (const float*)d_in[0];
    const int*   nbr  = (const int*)d_in[1];
    const int*   deg  = (const int*)d_in[2];

    const int n      = in_sizes[2];            // 16384
    const int maxdeg = in_sizes[1] / n;
    const int d      = in_sizes[0] / n;        // 256

    int*   headlist = (int*)d_ws;                                  // n ints
    uint4* pend_g   = (uint4*)(headlist + n);                      // n uint4 (256KB)
    unsigned short* hi_g = (unsigned short*)(pend_g + n);          // n * HROW u16

    float* out      = (float*)d_out;
    float* out_tail = out + (size_t)n * (size_t)d;   // head_mask .. num_clusters

    hipLaunchKernelGGL(k_prep, dim3((n + 255) / 256), dim3(256), 0, stream,
                       nbr, deg, maxdeg, n, pend_g, hi_g);

    hipLaunchKernelGGL(k_mis, dim3(1), dim3(TPB), 0, stream,
                       nbr, deg, maxdeg, n, pend_g, hi_g, headlist, out_tail);

    const int blocks = (n * 64 + 255) / 256;   // one wave per output row
    hipLaunchKernelGGL(k_avg, dim3(blocks), dim3(256), 0, stream,
                       vert, nbr, deg, maxdeg, n, headlist, out_tail, out);
}

// Round 12
// 85.552 us; speedup vs baseline: 3.0883x; 1.0215x over previous
//
#include <hip/hip_runtime.h>
#include <cstdint>
#include <cstddef>

// Problem constants (from reference): N=16384, D=256.
#define NV 16384
#define DD 256
#define TPB 1024           // k_mis threads (16 waves), 1 vertex/thread/block
#define BLK 1024
#define PCAP 7             // in-block lower-neighbor cap (P(Pois(0.5)>7) ~ 1e-8)
#define HROW 24            // u16 slots per vertex in hi_g: [0]=count, [1..23]=higher nbrs
#define NPASS 8            // probe passes per barrier round

// compiler memory barrier: forces LDS re-reads across passes WITHOUT ordering
// the loads within a pass against each other (volatile would serialize them)
#define CFENCE() asm volatile("" ::: "memory")

// ---------------------------------------------------------------------------
// K_prep (parallel, one pass over nbr): per vertex v emit
//  - pend_g[v] (uint4): in-1024-block lower neighbors as u16 offsets
//      x = count | e0<<16 ; y = e1|e2<<16 ; z = e3|e4<<16 ; w = e5|e6<<16
//  - hi_g[v*HROW..]: [count, up to 23 higher-neighbor vertex ids] (u16)
// ---------------------------------------------------------------------------
__global__ __launch_bounds__(256)
void k_prep(const int* __restrict__ nbr, const int* __restrict__ deg,
            int maxdeg, int n, uint4* __restrict__ pend_g,
            unsigned short* __restrict__ hi_g)
{
    int v = blockIdx.x * 256 + threadIdx.x;
    if (v >= n) return;
    const int b  = v & ~(BLK - 1);
    const int dv = deg[v];
    const int* __restrict__ row = nbr + (size_t)v * (size_t)maxdeg;
    unsigned short* __restrict__ hrow = hi_g + (size_t)v * HROW;
    unsigned w0 = 0, w1 = 0, w2 = 0, w3 = 0;
    int cnt = 0, hic = 0;
    for (int k = 0; k < dv; ++k) {
        int j = row[k];
        if (j > v) {
            if (hic < HROW - 1) hrow[1 + hic] = (unsigned short)j;
            ++hic;
        } else if (j >= b) {
            unsigned val = (unsigned)(j - b);
            switch (cnt) {
                case 0: w0 |= val << 16; break;
                case 1: w1 |= val;       break;
                case 2: w1 |= val << 16; break;
                case 3: w2 |= val;       break;
                case 4: w2 |= val << 16; break;
                case 5: w3 |= val;       break;
                case 6: w3 |= val << 16; break;
                default: break;
            }
            ++cnt;
        }
    }
    hrow[0] = (unsigned short)hic;
    w0 |= (unsigned)(cnt > 0xffff ? 0xffff : cnt);
    pend_g[v] = make_uint4(w0, w1, w2, w3);
}

// ---------------------------------------------------------------------------
// K_mis: lexicographic greedy MIS, single WG of 1024 threads (16 waves), PUSH.
// st: 0=unknown, 1=head, 2=nonhead (monotone -> LDS races benign).
// Heads push st=2 to higher neighbors from REGISTER-resident hi lists, so the
// out-of-block verdict is one st[v] read. Per round: up to NPASS probe passes;
// within a pass all probes are INDEPENDENT plain loads (one lgkmcnt batch);
// a compiler fence between passes forces genuine re-reads. Per-wave ballot
// early-exit; one drain-free barrier per round (lgkmcnt(0)+s_barrier keeps
// the next block's global prefetch in flight).
// ---------------------------------------------------------------------------
__global__ __launch_bounds__(TPB, 4)
void k_mis(const int* __restrict__ nbr, const int* __restrict__ deg,
           int maxdeg, int n,
           const uint4* __restrict__ pend_g, const unsigned short* __restrict__ hi_g,
           int* __restrict__ headlist, float* __restrict__ out_tail)
{
    __shared__ __align__(16) unsigned char st[NV];
    __shared__ int s_ws[TPB / 64];
    __shared__ int F[3];
    const int t    = threadIdx.x;
    const int lane = t & 63;
    const int wid  = t >> 6;

    ((uint4*)st)[t] = make_uint4(0u, 0u, 0u, 0u);   // 1024*16B == NV
    if (t < 3) F[t] = 0;
    __syncthreads();

    // prefetch block 0 (pend + hi row + deg), register double-buffered
    uint4 pv = make_uint4(0,0,0,0), h0 = pv, h1 = pv, h2 = pv;
    int   dv = 0;
    if (t < n) {
        pv = pend_g[t];
        const uint4* hp = (const uint4*)(hi_g + (size_t)t * HROW);
        h0 = hp[0]; h1 = hp[1]; h2 = hp[2];
        dv = deg[t];
    }
    int r = 0;

    for (int b = 0; b < n; b += BLK) {
        const int v = b + t;
        // prefetch next block; stays in flight across the drain-free barriers
        uint4 pn = make_uint4(0,0,0,0), n0 = pn, n1 = pn, n2 = pn;
        int   dn = 0;
        {
            int vn = b + BLK + t;
            if (vn < n) {
                pn = pend_g[vn];
                const uint4* hp = (const uint4*)(hi_g + (size_t)vn * HROW);
                n0 = hp[0]; n1 = hp[1]; n2 = hp[2];
                dn = deg[vn];
            }
        }

        const int np = pv.x & 0xffff;
        const int e0 = pv.x >> 16,    e1 = pv.y & 0xffff, e2 = pv.y >> 16;
        const int e3 = pv.z & 0xffff, e4 = pv.z >> 16;
        const int e5 = pv.w & 0xffff, e6 = pv.w >> 16;
        const int hic = (int)(h0.x & 0xffff);
        const int* __restrict__ row = nbr + (size_t)v * (size_t)maxdeg;

        int my = (v < n) ? 0 : 2;
        for (;; ++r) {
            if (t == 0) F[(r + 1) % 3] = 0;
            for (int pass = 0; pass < NPASS; ++pass) {
                if (my == 0) {
                    // batched INDEPENDENT probes (own status + up to 7 pend)
                    int qv = st[v];
                    int q0 = st[b + e0], q1 = st[b + e1], q2 = st[b + e2];
                    int q3 = st[b + e3], q4 = st[b + e4], q5 = st[b + e5];
                    int q6 = st[b + e6];
                    if (qv != 0) { my = 2; }
                    else {
                        bool anyH = false; int undec = 0;
                        if (np <= PCAP) {
                            if (np > 0) { anyH |= (q0 == 1); undec += (q0 == 0); }
                            if (np > 1) { anyH |= (q1 == 1); undec += (q1 == 0); }
                            if (np > 2) { anyH |= (q2 == 1); undec += (q2 == 0); }
                            if (np > 3) { anyH |= (q3 == 1); undec += (q3 == 0); }
                            if (np > 4) { anyH |= (q4 == 1); undec += (q4 == 0); }
                            if (np > 5) { anyH |= (q5 == 1); undec += (q5 == 0); }
                            if (np > 6) { anyH |= (q6 == 1); undec += (q6 == 0); }
                        } else {
                            for (int k = 0; k < dv; ++k) {
                                int j = row[k];
                                if (j >= b && j < v) {
                                    int q = st[j];
                                    anyH |= (q == 1); undec += (q == 0);
                                }
                            }
                        }
                        if (anyH) { my = 2; st[v] = 2; }
                        else if (undec == 0) {
                            my = 1;
                            st[v] = 1;
                            if (hic <= HROW - 1) {
                                // push from registers: entry i at u16 slot 1+i
                                #define PUSHE(word, sh, k) if ((k) < hic) st[((word) >> (sh)) & 0xffffu] = 2
                                PUSHE(h0.x,16, 0); PUSHE(h0.y, 0, 1); PUSHE(h0.y,16, 2);
                                PUSHE(h0.z, 0, 3); PUSHE(h0.z,16, 4); PUSHE(h0.w, 0, 5);
                                PUSHE(h0.w,16, 6);
                                PUSHE(h1.x, 0, 7); PUSHE(h1.x,16, 8); PUSHE(h1.y, 0, 9);
                                PUSHE(h1.y,16,10); PUSHE(h1.z, 0,11); PUSHE(h1.z,16,12);
                                PUSHE(h1.w, 0,13); PUSHE(h1.w,16,14);
                                PUSHE(h2.x, 0,15); PUSHE(h2.x,16,16); PUSHE(h2.y, 0,17);
                                PUSHE(h2.y,16,18); PUSHE(h2.z, 0,19); PUSHE(h2.z,16,20);
                                PUSHE(h2.w, 0,21); PUSHE(h2.w,16,22);
                                #undef PUSHE
                            } else {
                                for (int k = 0; k < dv; ++k) {
                                    int j = row[k];
                                    if (j > v) st[j] = 2;
                                }
                            }
                        }
                    }
                }
                if (__ballot(my == 0) == 0ULL) break;   // wave-local early out
                CFENCE();   // force genuine LDS re-reads next pass
            }
            if (my == 0) F[r % 3] = 1;
            // drain-free barrier: LDS visible, global prefetch stays in flight
            asm volatile("s_waitcnt lgkmcnt(0)\n\ts_barrier" ::: "memory");
            if (F[r % 3] == 0) { ++r; break; }
        }
        pv = pn; h0 = n0; h1 = n1; h2 = n2; dv = dn;
    }

    // ---- epilogue: count heads, scan, emit headlist / head_mask / count ----
    uint4 qq = ((const uint4*)st)[t];          // thread t owns bytes [16t,16t+16)
    int cnt = __popc(qq.x & 0x01010101u) + __popc(qq.y & 0x01010101u)
            + __popc(qq.z & 0x01010101u) + __popc(qq.w & 0x01010101u);
    int c = cnt;
    #pragma unroll
    for (int off = 1; off < 64; off <<= 1) {
        int x = __shfl_up(c, off);
        if (lane >= off) c += x;
    }
    if (lane == 63) s_ws[wid] = c;
    __syncthreads();
    int wexcl = 0, tot = 0;
    #pragma unroll
    for (int w = 0; w < TPB / 64; ++w) {
        int s = s_ws[w];
        tot += s;
        if (w < wid) wexcl += s;
    }
    int excl = wexcl + (c - cnt);
    #pragma unroll
    for (int i = 0; i < 16; ++i) {
        int v = t * 16 + i;
        if (st[v] == 1) { headlist[excl] = v; ++excl; }
    }
    for (int i = t; i < NV / 4; i += TPB) {
        unsigned w = ((const unsigned*)st)[i];
        float4 f;
        f.x = (float)(w & 1u);         f.y = (float)((w >> 8) & 1u);
        f.z = (float)((w >> 16) & 1u); f.w = (float)((w >> 24) & 1u);
        ((float4*)out_tail)[i] = f;
    }
    if (t == 0) out_tail[n] = (float)tot;
}

// ---------------------------------------------------------------------------
// K_avg (fused owner+avg): one 64-lane wave per output row.
// Waves [0,tot): cluster mean for h=headlist[w]. Candidate j in row(h) is a
// member iff j nonhead AND min{head nbrs of j} == h (walk j's row in-lane;
// j<h auto-excluded since its min head nbr < j < h).
// Waves [tot,n): zero-fill the row (replaces the memset).
// ---------------------------------------------------------------------------
__global__ __launch_bounds__(256)
void k_avg(const float* __restrict__ vert, const int* __restrict__ nbr,
           const int* __restrict__ deg, int maxdeg, int n,
           const int* __restrict__ headlist,
           const float* __restrict__ tail, float* __restrict__ out)
{
    const int w    = (blockIdx.x * 256 + threadIdx.x) >> 6;
    const int lane = threadIdx.x & 63;
    if (w >= n) return;
    const int tot  = (int)tail[n];
    if (w >= tot) {
        reinterpret_cast<float4*>(out + (size_t)w * DD)[lane] = make_float4(0.f, 0.f, 0.f, 0.f);
        return;
    }
    const int h = headlist[w];

    const int dh = deg[h];
    const int* __restrict__ row = nbr + (size_t)h * (size_t)maxdeg;

    float4 acc = reinterpret_cast<const float4*>(vert + (size_t)h * DD)[lane];
    int cnt = 1;

    for (int k0 = 0; k0 < dh; k0 += 64) {
        int k = k0 + lane;
        int j = (k < dh) ? row[k] : -1;
        bool mem = false;
        if (j > h && tail[j] == 0.0f) {        // nonhead, higher candidate
            const int dj = deg[j];
            const int* __restrict__ rj = nbr + (size_t)j * (size_t)maxdeg;
            int mn = 0x7fffffff;
            for (int kk = 0; kk < dj; ++kk) {
                int u = rj[kk];
                if (tail[u] != 0.0f) mn = min(mn, u);
            }
            mem = (mn == h);
        }
        unsigned long long m = __ballot(mem);
        cnt += __popcll(m);
        while (m) {
            int bit = __ffsll((long long)m) - 1;
            m &= (m - 1);
            int jj = __shfl(j, bit);
            float4 rr = reinterpret_cast<const float4*>(vert + (size_t)jj * DD)[lane];
            acc.x += rr.x; acc.y += rr.y; acc.z += rr.z; acc.w += rr.w;
        }
    }
    const float inv = 1.0f / (float)cnt;
    float4 res;
    res.x = acc.x * inv; res.y = acc.y * inv;
    res.z = acc.z * inv; res.w = acc.w * inv;
    reinterpret_cast<float4*>(out + (size_t)w * DD)[lane] = res;
}

// ---------------------------------------------------------------------------
extern "C" void kernel_launch(void* const* d_in, const int* in_sizes, int n_in,
                              void* d_out, int out_size, void* d_ws, size_t ws_size,
                              hipStream_t stream)
{
    const float* vert = (const float*)d_in[0];
    const int*   nbr  = (const int*)d_in[1];
    const int*   deg  = (const int*)d_in[2];

    const int n      = in_sizes[2];            // 16384
    const int maxdeg = in_sizes[1] / n;
    const int d      = in_sizes[0] / n;        // 256

    int*   headlist = (int*)d_ws;                                  // n ints
    uint4* pend_g   = (uint4*)(headlist + n);                      // n uint4 (256KB)
    unsigned short* hi_g = (unsigned short*)(pend_g + n);          // n * HROW u16

    float* out      = (float*)d_out;
    float* out_tail = out + (size_t)n * (size_t)d;   // head_mask .. num_clusters

    hipLaunchKernelGGL(k_prep, dim3((n + 255) / 256), dim3(256), 0, stream,
                       nbr, deg, maxdeg, n, pend_g, hi_g);

    hipLaunchKernelGGL(k_mis, dim3(1), dim3(TPB), 0, stream,
                       nbr, deg, maxdeg, n, pend_g, hi_g, headlist, out_tail);

    const int blocks = (n * 64 + 255) / 256;   // one wave per output row
    hipLaunchKernelGGL(k_avg, dim3(blocks), dim3(256), 0, stream,
                       vert, nbr, deg, maxdeg, n, headlist, out_tail, out);
}